// Round 1
// baseline (40.280 us; speedup 1.0000x reference)
//
#include <hip/hip_runtime.h>
#include <hip/hip_bf16.h>

// RoIPooling: features (2048, 512, 7, 7) f32, landmarks (2048, 16) i32.
// out[b][l*512 + ch] = max over 2x2 window of features[b][ch][x1..x1+1][y1..y1+1]
// where x1 = clip(lm[b][2l]*7/224 - 1, 0, 5), y1 = clip(lm[b][2l+1]*7/224 - 1, 0, 5).

#define FEAT_HW 7
#define IMG_SIZE 224
#define N_LM 8
#define NCH 512
#define CH_PER_BLK 256          // channels handled per block
#define PLANE (FEAT_HW * FEAT_HW)   // 49

__global__ __launch_bounds__(256)
void RoIPooling_52424370815307_kernel(const float* __restrict__ feat,
                                      const int* __restrict__ lm,
                                      float* __restrict__ out) {
    const int blk  = blockIdx.x;        // 0 .. 2*B-1
    const int b    = blk >> 1;
    const int c0   = (blk & 1) * CH_PER_BLK;
    const int tid  = threadIdx.x;

    extern __shared__ float lds[];      // CH_PER_BLK * 49 floats = 50176 B
    __shared__ int sx1[N_LM], sy1[N_LM];

    // ---- stage 256 channel planes (50 KB) into LDS, coalesced float4 ----
    // base offset in floats: b*512*49 + c0*49; both multiples of 4 (25088, 12544)
    const float4* __restrict__ src =
        (const float4*)(feat + (size_t)b * (NCH * PLANE) + (size_t)c0 * PLANE);
    float4* dst4 = (float4*)lds;
    constexpr int N4 = CH_PER_BLK * PLANE / 4;   // 3136
    #pragma unroll 4
    for (int i = tid; i < N4; i += 256) dst4[i] = src[i];

    // ---- landmark window starts ----
    if (tid < N_LM) {
        int x = lm[b * 16 + 2 * tid];
        int y = lm[b * 16 + 2 * tid + 1];
        int x1 = x * FEAT_HW / IMG_SIZE - 1;
        x1 = x1 < 0 ? 0 : (x1 > FEAT_HW - 2 ? FEAT_HW - 2 : x1);
        int y1 = y * FEAT_HW / IMG_SIZE - 1;
        y1 = y1 < 0 ? 0 : (y1 > FEAT_HW - 2 ? FEAT_HW - 2 : y1);
        sx1[tid] = x1;
        sy1[tid] = y1;
    }
    __syncthreads();

    // ---- compute: thread tid owns channel (c0 + tid) ----
    // LDS read stride per lane = 49 floats (odd) -> conflict-free (2 lanes/bank)
    const float* __restrict__ plane = lds + tid * PLANE;
    float* __restrict__ outb = out + (size_t)b * (N_LM * NCH) + c0 + tid;

    #pragma unroll
    for (int l = 0; l < N_LM; ++l) {
        const int o = sx1[l] * FEAT_HW + sy1[l];
        const float v0 = plane[o];
        const float v1 = plane[o + 1];
        const float v2 = plane[o + FEAT_HW];
        const float v3 = plane[o + FEAT_HW + 1];
        outb[(size_t)l * NCH] = fmaxf(fmaxf(v0, v1), fmaxf(v2, v3));
    }
}

extern "C" void kernel_launch(void* const* d_in, const int* in_sizes, int n_in,
                              void* d_out, int out_size, void* d_ws, size_t ws_size,
                              hipStream_t stream) {
    const float* feat = (const float*)d_in[0];
    const int*   lm   = (const int*)d_in[1];
    float*       out  = (float*)d_out;

    const int B = in_sizes[1] / 16;                 // 2048
    const int grid = B * (NCH / CH_PER_BLK);        // 4096
    const size_t lds_bytes = (size_t)CH_PER_BLK * PLANE * sizeof(float); // 50176

    RoIPooling_52424370815307_kernel<<<grid, 256, lds_bytes, stream>>>(feat, lm, out);
}